// Round 1
// baseline (1035.076 us; speedup 1.0000x reference)
//
#include <hip/hip_runtime.h>

// Local_Layer (GAT-style): per node n, per head h:
//   score[m,h] = relu( q[n,h,:]·W[h,0:16] + k[n,m,h,:]·W[h,16:32] + b[h] )
//   attn = softmax_m(score);  out[n,h*16+d] = sum_m attn[m,h]*s[n,m,h*16+d]
//
// N=50000, M=32, H=8, D=16, HID=128. All f32.
// HBM-bound: s is 819 MB and must be read exactly once -> stage per-node
// 16KB tile in LDS; both consuming passes read it from LDS.

#define MM   32
#define HH   8
#define DD   16
#define HIDC 128
#define SROW 129   // odd stride: pass-A (stride-16 per lane) and pass-B
                   // (lane-consecutive) LDS reads both conflict-free

__global__ __launch_bounds__(256, 4)
void gat_kernel(const float* __restrict__ hq,   // [N,128] query features
                const float* __restrict__ s,    // [N,32,128] neighbor K=V
                const float* __restrict__ W,    // [8,32]
                const float* __restrict__ b,    // [8]
                float* __restrict__ out)        // [N,128]
{
    __shared__ float s_tile[MM * SROW];   // 16512 B
    __shared__ float qdot_sh[HH];         // per-head q·Wq + b
    __shared__ float attn_sh[MM * 9];     // stride 9: conflict-free write

    const int t = threadIdx.x;
    const int n = blockIdx.x;
    const size_t sbase = (size_t)n * (MM * HIDC);

    // ---- stage s[n]: coalesced float4 global loads (1 KiB/wave/inst) ----
    const float4* sg = reinterpret_cast<const float4*>(s + sbase);
    float4 v[4];
#pragma unroll
    for (int j = 0; j < 4; ++j) v[j] = sg[t + 256 * j];

    // ---- preload Wk (my pass-A head's key weights) into 16 VGPRs.
    // W is 1 KB -> L1-hot after first block on each CU.
    const int mA = t & 31;   // pass-A neighbor index
    const int hA = t >> 5;   // pass-A head index
    float wk[16];
    {
        const float4* wg = reinterpret_cast<const float4*>(W + hA * 32 + 16);
#pragma unroll
        for (int j = 0; j < 4; ++j) {
            float4 w4 = wg[j];
            wk[4 * j + 0] = w4.x; wk[4 * j + 1] = w4.y;
            wk[4 * j + 2] = w4.z; wk[4 * j + 3] = w4.w;
        }
    }

    // LDS writes: scalar b32 (odd stride breaks b128 alignment); 4-way
    // conflict on writes, accepted (small share of LDS pipe).
#pragma unroll
    for (int j = 0; j < 4; ++j) {
        int idx = t + 256 * j;          // float4 index within the tile
        int m = idx >> 5;               // row (neighbor)
        int c = (idx & 31) << 2;        // column (channel)
        float* dst = &s_tile[m * SROW + c];
        dst[0] = v[j].x; dst[1] = v[j].y; dst[2] = v[j].z; dst[3] = v[j].w;
    }

    // ---- qdot[h] = q·W[h,0:16] + b[h]; 16-lane shuffle reduction ----
    if (t < HIDC) {
        int hh = t >> 4, e = t & 15;
        float p = hq[(size_t)n * HIDC + t] * W[hh * 32 + e];
#pragma unroll
        for (int off = 8; off; off >>= 1) p += __shfl_xor(p, off, 16);
        if (e == 0) qdot_sh[hh] = p + b[hh];
    }

    __syncthreads();

    // ---- pass A: score + softmax over m (32-lane groups == m-groups) ----
    {
        float kdot = 0.f;
        const float* srow = &s_tile[mA * SROW + hA * DD];
#pragma unroll
        for (int e = 0; e < 16; ++e) kdot += srow[e] * wk[e];
        float score = fmaxf(kdot + qdot_sh[hA], 0.f);   // relu

        float mx = score;
#pragma unroll
        for (int off = 16; off; off >>= 1) mx = fmaxf(mx, __shfl_xor(mx, off, 32));
        float es = __expf(score - mx);
        float sum = es;
#pragma unroll
        for (int off = 16; off; off >>= 1) sum += __shfl_xor(sum, off, 32);

        attn_sh[mA * 9 + hA] = es / sum;
    }

    __syncthreads();

    // ---- pass B: out[c] = sum_m attn[m, c/16] * s_tile[m, c] ----
    // lane-consecutive LDS reads (conflict-free); attn reads broadcast.
    if (t < HIDC) {
        int hB = t >> 4;
        float acc = 0.f;
#pragma unroll 8
        for (int m = 0; m < MM; ++m)
            acc += attn_sh[m * 9 + hB] * s_tile[m * SROW + t];
        out[(size_t)n * HIDC + t] = acc;
    }
}

extern "C" void kernel_launch(void* const* d_in, const int* in_sizes, int n_in,
                              void* d_out, int out_size, void* d_ws, size_t ws_size,
                              hipStream_t stream) {
    const float* hq = (const float*)d_in[0];   // [N,128]
    const float* s  = (const float*)d_in[1];   // [N,32,128]
    const float* W  = (const float*)d_in[2];   // [8,32]
    const float* b  = (const float*)d_in[3];   // [8]
    float* out = (float*)d_out;

    const int N = in_sizes[0] / HIDC;          // 50000
    gat_kernel<<<dim3(N), dim3(256), 0, stream>>>(hq, s, W, b, out);
}